// Round 11
// baseline (49.418 us; speedup 1.0000x reference)
//
#include <hip/hip_runtime.h>

// Grayscale morphological dilation, 7x7 additive SE, zero 'same' padding:
//   out[p, i, j] = max_{a,b in 0..6} ( xz(p, i+a-3, j+b-3) + w[a,b] )
//
// R11: LDS ring staging. R7-R10 showed the limiter is the private-halo
// register tiling (5.25x L1 read amplification, 42 wave-VMEM/thread) --
// VALU cuts (R9) and prefetch depth (R10) both bounced off ~40-42us.
// New structure: block 256 th, tile 256 cols x 64 rows = 4 bands x 16 rows.
// LDS = 38-row x 264-col f32 RING (40,128 B -> 4 blocks/CU, grid 1024 =
// exact residency). Slot s holds global row row0blk-3+o, s = o mod 38.
// Per band b: (1) issue next band's 16 rows as 5 global_load_dwordx4 into
// regs (T14 issue-early), (2) compute band b from LDS (3 ds_read_b128/row,
// conflict-free), (3) ds_write the staged rows (write-late), barrier.
// Stage slots are disjoint from the compute window mod 38, and each batch
// overwrites only slots last read by the PREVIOUS band (barrier-ordered).
// Compute core = R9's pk_add/max3 (bit-exact fp32). Literal indices only.

#define HH 512
#define WW 512

typedef float v2f __attribute__((ext_vector_type(2)));

__device__ __align__(16) const float ZP4[4] = {0.f, 0.f, 0.f, 0.f};

__device__ __forceinline__ float max3f(float a, float b, float c) {
  float d;
  asm("v_max3_f32 %0, %1, %2, %3" : "=v"(d) : "v"(a), "v"(b), "v"(c));
  return d;
}

// ---- compute core (identical math to R9; E[] = floats col0-4 .. col0+7) ---
#define ONEOUT(T, K, J, P1, P2, P3, S)                                       \
  {                                                                          \
    const int a_ = (K) - (T);                                                \
    const v2f c01_ = (P1) + w2[a_][0];          /* v_pk_add_f32 */           \
    const v2f c23_ = (P2) + w2[a_][1];                                       \
    const v2f c45_ = (P3) + w2[a_][2];                                       \
    const float c6_ = (S) + w6[a_];                                          \
    const float t1_ = max3f(c01_.x, c01_.y, c23_.x);                         \
    const float t2_ = max3f(c23_.y, c45_.x, c45_.y);                         \
    acc[T][J] = ((K) == (T))                                                 \
                    ? max3f(t1_, t2_, c6_)               /* first touch */   \
                    : max3f(t1_, t2_, fmaxf(c6_, acc[T][J]));                \
  }

#define COMPROW(E, K)                                                        \
  {                                                                          \
    const v2f o0_ = (v2f){E[0].y, E[1].x};                                   \
    const v2f o1_ = (v2f){E[1].y, E[2].x};                                   \
    const v2f o2_ = (v2f){E[2].y, E[3].x};                                   \
    const v2f o3_ = (v2f){E[3].y, E[4].x};                                   \
    _Pragma("unroll") for (int t = 0; t < 4; ++t) {                          \
      if (t <= (K) && t + 6 >= (K)) {                                        \
        ONEOUT(t, K, 0, o0_, o1_, o2_, E[3].y);                              \
        ONEOUT(t, K, 1, E[1], E[2], E[3], E[4].x);                           \
        ONEOUT(t, K, 2, o1_, o2_, o3_, E[4].y);                              \
        ONEOUT(t, K, 3, E[2], E[3], E[4], E[5].x);                           \
      }                                                                      \
    }                                                                        \
  }

// LDS row read: ring offset o = 16b + tr4 + K, slot = o mod 38.
#define LOADDS(E, K)                                                         \
  {                                                                          \
    int o_ = bando + tr4 + (K);                                              \
    o_ -= (o_ >= 38) ? 38 : 0;                                               \
    const float* lr_ = ldsf + o_ * 264 + lc4;                                \
    float4 v0_ = *reinterpret_cast<const float4*>(lr_);                      \
    float4 v1_ = *reinterpret_cast<const float4*>(lr_ + 4);                  \
    float4 v2_ = *reinterpret_cast<const float4*>(lr_ + 8);                  \
    E[0] = (v2f){v0_.x, v0_.y};  E[1] = (v2f){v0_.z, v0_.w};                 \
    E[2] = (v2f){v1_.x, v1_.y};  E[3] = (v2f){v1_.z, v1_.w};                 \
    E[4] = (v2f){v2_.x, v2_.y};  E[5] = (v2f){v2_.z, v2_.w};                 \
  }

#define STOREROW4(T)                                                         \
  {                                                                          \
    float* orow_ = op + (ptrdiff_t)(rowband + tr4 + (T)) * WW + col0;        \
    *reinterpret_cast<float4*>(orow_) =                                      \
        make_float4(acc[T][0], acc[T][1], acc[T][2], acc[T][3]);             \
  }

__global__ __launch_bounds__(256) void dilate7(const float* __restrict__ x,
                                               const float* __restrict__ wg,
                                               float* __restrict__ out) {
  __shared__ float ldsf[38 * 264];               // 40,128 B ring

  const int tid = threadIdx.x;
  const int lc = tid & 63;
  const int lc4 = lc << 2;
  const int colbase = blockIdx.x * 256;          // scalar
  const int col0 = colbase + lc4;
  const int tr4 = __builtin_amdgcn_readfirstlane((tid >> 6) << 2);  // wave row*4
  const int row0blk = blockIdx.y * 64;

  const size_t plane_off = (size_t)blockIdx.z * (size_t)(HH * WW);
  const float* xp = x + plane_off;
  float* op = out + plane_off;

  // Weights -> SGPRs, packed pairs.
  float wv[49];
#pragma unroll
  for (int i = 0; i < 49; ++i)
    wv[i] = __int_as_float(__builtin_amdgcn_readfirstlane(__float_as_int(wg[i])));
  v2f w2[7][3];
  float w6[7];
#pragma unroll
  for (int a = 0; a < 7; ++a) {
    w2[a][0] = (v2f){wv[7 * a + 0], wv[7 * a + 1]};
    w2[a][1] = (v2f){wv[7 * a + 2], wv[7 * a + 3]};
    w2[a][2] = (v2f){wv[7 * a + 4], wv[7 * a + 5]};
    w6[a] = wv[7 * a + 6];
  }

  // ---- Prologue: stage ring slots 0..21 (rows row0blk-3 .. +18) ----
  // chunk q = i*256+tid -> r = q/66, c = q%66; lds[r*264 + 4c] = x[row0blk-3+r][colbase-4+4c]
  {
    unsigned r_ = __umulhi((unsigned)tid, 0x7C1F07C4u) >> 5;   // tid/66
    int c_ = tid - (int)r_ * 66;
#pragma unroll
    for (int i = 0; i < 6; ++i) {
      int q = i * 256 + tid;
      if (q < 1452) {                                          // 22*66 chunks
        int g = row0blk - 3 + (int)r_;
        int gc = colbase - 4 + (c_ << 2);
        bool ok = ((unsigned)g < (unsigned)HH) && ((unsigned)gc < (unsigned)WW);
        const float* src = ok ? (xp + (ptrdiff_t)g * WW + gc) : &ZP4[0];
        float4 v = *reinterpret_cast<const float4*>(src);
        *reinterpret_cast<float4*>(ldsf + (int)r_ * 264 + (c_ << 2)) = v;
      }
      r_ += 3; c_ += 58; if (c_ >= 66) { c_ -= 66; ++r_; }     // q += 256
    }
  }
  __syncthreads();

  float acc[4][4];
  v2f rvA[6], rvB[6];

#pragma unroll 1
  for (int b = 0; b < 4; ++b) {
    const int bando = 16 * b;
    const int rowband = row0blk + bando;

    // ---- T14 issue-early: next band's 16 rows (o = 16b+22 .. +37) ----
    float4 sv[5];
    if (b < 3) {
      unsigned r_ = __umulhi((unsigned)tid, 0x7C1F07C4u) >> 5;
      int c_ = tid - (int)r_ * 66;
      const int grb = row0blk + bando + 19;                    // row0blk-3+(16b+22)
#pragma unroll
      for (int i = 0; i < 5; ++i) {
        if (i < 4 || tid < 32) {                               // 16*66=1056 chunks
          int g = grb + (int)r_;
          int gc = colbase - 4 + (c_ << 2);
          bool ok = ((unsigned)g < (unsigned)HH) && ((unsigned)gc < (unsigned)WW);
          const float* src = ok ? (xp + (ptrdiff_t)g * WW + gc) : &ZP4[0];
          sv[i] = *reinterpret_cast<const float4*>(src);
        }
        r_ += 3; c_ += 58; if (c_ >= 66) { c_ -= 66; ++r_; }
      }
    }

    // ---- Compute band b from LDS (rows o = 16b .. 16b+21) ----
    LOADDS(rvA, 0);
    LOADDS(rvB, 1);  COMPROW(rvA, 0);
    LOADDS(rvA, 2);  COMPROW(rvB, 1);
    LOADDS(rvB, 3);  COMPROW(rvA, 2);
    LOADDS(rvA, 4);  COMPROW(rvB, 3);
    LOADDS(rvB, 5);  COMPROW(rvA, 4);
    LOADDS(rvA, 6);  COMPROW(rvB, 5);
    LOADDS(rvB, 7);  COMPROW(rvA, 6);  STOREROW4(0);
    LOADDS(rvA, 8);  COMPROW(rvB, 7);  STOREROW4(1);
    LOADDS(rvB, 9);  COMPROW(rvA, 8);  STOREROW4(2);
                     COMPROW(rvB, 9);  STOREROW4(3);

    // ---- write-late: commit staged rows to ring slots (16b+22..37 mod 38) --
    if (b < 3) {
      unsigned r_ = __umulhi((unsigned)tid, 0x7C1F07C4u) >> 5;
      int c_ = tid - (int)r_ * 66;
      int sb = bando + 22; sb -= (sb >= 38) ? 38 : 0;          // {22,0,16}
#pragma unroll
      for (int i = 0; i < 5; ++i) {
        if (i < 4 || tid < 32) {
          *reinterpret_cast<float4*>(ldsf + (sb + (int)r_) * 264 + (c_ << 2)) = sv[i];
        }
        r_ += 3; c_ += 58; if (c_ >= 66) { c_ -= 66; ++r_; }
      }
      __syncthreads();
    }
  }
}

extern "C" void kernel_launch(void* const* d_in, const int* in_sizes, int n_in,
                              void* d_out, int out_size, void* d_ws, size_t ws_size,
                              hipStream_t stream) {
  const float* x = (const float*)d_in[0];
  const float* w = (const float*)d_in[1];
  float* out = (float*)d_out;
  const int planes = in_sizes[0] / (HH * WW);   // 8*8 = 64
  dim3 grid(2, 8, planes);                      // 256x64 tile -> exact cover
  dilate7<<<grid, dim3(256, 1, 1), 0, stream>>>(x, w, out);
}

// Round 12
// 46.628 us; speedup vs baseline: 1.0598x; 1.0598x over previous
//
#include <hip/hip_runtime.h>

// Grayscale morphological dilation, 7x7 additive SE, zero 'same' padding:
//   out[p, i, j] = max_{a,b in 0..6} ( xz(p, i+a-3, j+b-3) + w[a,b] )
//
// R12 = R11's LDS ring, with the two measured regressions fixed:
//  (a) staging via __builtin_amdgcn_global_load_lds width=16 (no register
//      roundtrip -> no sv[] scratch spill, no ds_write phase at all);
//  (b) LDS declared float4[] (guaranteed 16B alignment -> native
//      ds_read_b128; R11's float[]+reinterpret_cast legalized to b32/b64
//      reads whose 16B lane stride = 8-way bank conflict, 8.26M counts).
// Schedule = T3 "minimum 2-phase": per band, issue next band's 16 rows
// (5 global_load_lds/thread, lane-linear dest = the one layout the HW
// supports), compute current band from LDS, one __syncthreads() (the
// vmcnt(0) drain is free: loads were issued ~2000 cyc earlier).
// Ring: 38 slots x 66 float4 (40,128 B -> 4 blocks/CU, grid 1024 = exact
// residency). Slot s holds global row row0blk-3+o, s = o mod 38; band b
// reads o = 16b..16b+21, prefetch writes o = 16b+22..16b+37 (disjoint;
// slots being overwritten were last read in band b-1, behind a barrier).
// Compute core = R9 pk_add/max3, bit-exact fp32, literal indices only.

#define HH 512
#define WW 512

typedef float v2f __attribute__((ext_vector_type(2)));

__device__ __align__(16) const float ZP4[4] = {0.f, 0.f, 0.f, 0.f};

__device__ __forceinline__ float max3f(float a, float b, float c) {
  float d;
  asm("v_max3_f32 %0, %1, %2, %3" : "=v"(d) : "v"(a), "v"(b), "v"(c));
  return d;
}

__device__ __forceinline__ void gl_lds16(const float* g, void* l) {
  __builtin_amdgcn_global_load_lds(
      (const __attribute__((address_space(1))) void*)g,
      (__attribute__((address_space(3))) void*)l, 16, 0, 0);
}

// Stage NC 16B-chunks (chunk q: r=q/66, c=q%66 -> global row GRB+r, col
// colbase-4+4c, OOB -> zero page) into ring slots starting at SLOT.
// LDS dest is lane-linear: chunk q lands at ring[SLOT*66 + q] via
// wave-uniform base + lane*16 (global src addr is per-lane).
#define STAGE(SLOT, GRB, NC)                                                 \
  {                                                                          \
    unsigned r_ = __umulhi((unsigned)tid, 0x7C1F07C4u) >> 5; /* tid/66 */    \
    int c_ = tid - (int)r_ * 66;                                             \
    _Pragma("unroll") for (int i_ = 0; i_ < ((NC) + 255) / 256; ++i_) {      \
      int q_ = i_ * 256 + tid;                                               \
      if (q_ < (NC)) {                                                       \
        int g_ = (GRB) + (int)r_;                                            \
        int gc_ = colbase - 4 + (c_ << 2);                                   \
        bool ok_ = ((unsigned)g_ < (unsigned)HH) &&                          \
                   ((unsigned)gc_ < (unsigned)WW);                           \
        const float* src_ = ok_ ? (xp + (ptrdiff_t)g_ * WW + gc_) : &ZP4[0]; \
        void* dst_ =                                                         \
            (void*)((char*)(ring + (SLOT) * 66) + ((i_ * 256 + w64) << 4));  \
        gl_lds16(src_, dst_);                                                \
      }                                                                      \
      r_ += 3; c_ += 58; if (c_ >= 66) { c_ -= 66; ++r_; }   /* q += 256 */  \
    }                                                                        \
  }

// ---- compute core (identical math to R9/R11; E[] = cols col0-4..col0+7) --
#define ONEOUT(T, K, J, P1, P2, P3, S)                                       \
  {                                                                          \
    const int a_ = (K) - (T);                                                \
    const v2f c01_ = (P1) + w2[a_][0];          /* v_pk_add_f32 */           \
    const v2f c23_ = (P2) + w2[a_][1];                                       \
    const v2f c45_ = (P3) + w2[a_][2];                                       \
    const float c6_ = (S) + w6[a_];                                          \
    const float t1_ = max3f(c01_.x, c01_.y, c23_.x);                         \
    const float t2_ = max3f(c23_.y, c45_.x, c45_.y);                         \
    acc[T][J] = ((K) == (T))                                                 \
                    ? max3f(t1_, t2_, c6_)               /* first touch */   \
                    : max3f(t1_, t2_, fmaxf(c6_, acc[T][J]));                \
  }

#define COMPROW(E, K)                                                        \
  {                                                                          \
    const v2f o0_ = (v2f){E[0].y, E[1].x};                                   \
    const v2f o1_ = (v2f){E[1].y, E[2].x};                                   \
    const v2f o2_ = (v2f){E[2].y, E[3].x};                                   \
    const v2f o3_ = (v2f){E[3].y, E[4].x};                                   \
    _Pragma("unroll") for (int t = 0; t < 4; ++t) {                          \
      if (t <= (K) && t + 6 >= (K)) {                                        \
        ONEOUT(t, K, 0, o0_, o1_, o2_, E[3].y);                              \
        ONEOUT(t, K, 1, E[1], E[2], E[3], E[4].x);                           \
        ONEOUT(t, K, 2, o1_, o2_, o3_, E[4].y);                              \
        ONEOUT(t, K, 3, E[2], E[3], E[4], E[5].x);                           \
      }                                                                      \
    }                                                                        \
  }

// LDS row read: ring offset o = 16b + tr4 + K, slot = o mod 38; lane reads
// float4 chunks lc, lc+1, lc+2 (stride-16B consecutive -> conflict-free).
#define LOADDS(E, K)                                                         \
  {                                                                          \
    int o_ = bando + tr4 + (K);                                              \
    o_ -= (o_ >= 38) ? 38 : 0;                                               \
    const float4* lr_ = ring + o_ * 66 + lc;                                 \
    float4 v0_ = lr_[0];                                                     \
    float4 v1_ = lr_[1];                                                     \
    float4 v2_ = lr_[2];                                                     \
    E[0] = (v2f){v0_.x, v0_.y};  E[1] = (v2f){v0_.z, v0_.w};                 \
    E[2] = (v2f){v1_.x, v1_.y};  E[3] = (v2f){v1_.z, v1_.w};                 \
    E[4] = (v2f){v2_.x, v2_.y};  E[5] = (v2f){v2_.z, v2_.w};                 \
  }

#define STOREROW4(T)                                                         \
  {                                                                          \
    float* orow_ = op + (ptrdiff_t)(rowband + tr4 + (T)) * WW + col0;        \
    *reinterpret_cast<float4*>(orow_) =                                      \
        make_float4(acc[T][0], acc[T][1], acc[T][2], acc[T][3]);             \
  }

__global__ __launch_bounds__(256) void dilate7(const float* __restrict__ x,
                                               const float* __restrict__ wg,
                                               float* __restrict__ out) {
  __shared__ float4 ring[38 * 66];               // 40,128 B ring

  const int tid = threadIdx.x;
  const int lc = tid & 63;                       // float4-chunk index in row
  const int colbase = blockIdx.x * 256;          // scalar
  const int col0 = colbase + (lc << 2);
  const int tr4 = __builtin_amdgcn_readfirstlane((tid >> 6) << 2);
  const int w64 = __builtin_amdgcn_readfirstlane((tid >> 6) << 6);
  const int row0blk = blockIdx.y * 64;

  const size_t plane_off = (size_t)blockIdx.z * (size_t)(HH * WW);
  const float* xp = x + plane_off;
  float* op = out + plane_off;

  // Weights -> SGPRs, packed pairs.
  float wv[49];
#pragma unroll
  for (int i = 0; i < 49; ++i)
    wv[i] = __int_as_float(__builtin_amdgcn_readfirstlane(__float_as_int(wg[i])));
  v2f w2[7][3];
  float w6[7];
#pragma unroll
  for (int a = 0; a < 7; ++a) {
    w2[a][0] = (v2f){wv[7 * a + 0], wv[7 * a + 1]};
    w2[a][1] = (v2f){wv[7 * a + 2], wv[7 * a + 3]};
    w2[a][2] = (v2f){wv[7 * a + 4], wv[7 * a + 5]};
    w6[a] = wv[7 * a + 6];
  }

  // Prologue: fill ring slots 0..21 (global rows row0blk-3 .. +18).
  STAGE(0, row0blk - 3, 1452);
  __syncthreads();

  float acc[4][4];
  v2f rvA[6], rvB[6];

#pragma unroll 1
  for (int b = 0; b < 4; ++b) {
    const int bando = 16 * b;
    const int rowband = row0blk + bando;

    // Phase 1: issue next band's 16 rows direct-to-LDS (slots 16b+22..+37
    // mod 38 = {22,0,16}; rows rowband+19 .. +34). Loads stay in flight
    // through the compute phase; drained by the barrier below.
    if (b < 3) {
      int sb = bando + 22;
      sb -= (sb >= 38) ? 38 : 0;
      STAGE(sb, rowband + 19, 1056);
    }

    // Phase 2: compute band b from LDS (ring offsets 16b .. 16b+21).
    LOADDS(rvA, 0);
    LOADDS(rvB, 1);  COMPROW(rvA, 0);
    LOADDS(rvA, 2);  COMPROW(rvB, 1);
    LOADDS(rvB, 3);  COMPROW(rvA, 2);
    LOADDS(rvA, 4);  COMPROW(rvB, 3);
    LOADDS(rvB, 5);  COMPROW(rvA, 4);
    LOADDS(rvA, 6);  COMPROW(rvB, 5);
    LOADDS(rvB, 7);  COMPROW(rvA, 6);  STOREROW4(0);
    LOADDS(rvA, 8);  COMPROW(rvB, 7);  STOREROW4(1);
    LOADDS(rvB, 9);  COMPROW(rvA, 8);  STOREROW4(2);
                     COMPROW(rvB, 9);  STOREROW4(3);

    __syncthreads();   // vmcnt(0)+barrier: prefetch landed, window advances
  }
}

extern "C" void kernel_launch(void* const* d_in, const int* in_sizes, int n_in,
                              void* d_out, int out_size, void* d_ws, size_t ws_size,
                              hipStream_t stream) {
  const float* x = (const float*)d_in[0];
  const float* w = (const float*)d_in[1];
  float* out = (float*)d_out;
  const int planes = in_sizes[0] / (HH * WW);   // 8*8 = 64
  dim3 grid(2, 8, planes);                      // 256x64 tile -> exact cover
  dilate7<<<grid, dim3(256, 1, 1), 0, stream>>>(x, w, out);
}

// Round 13
// 42.057 us; speedup vs baseline: 1.1750x; 1.1087x over previous
//
#include <hip/hip_runtime.h>

// Grayscale morphological dilation, 7x7 additive SE, zero 'same' padding:
//   out[p, i, j] = max_{a,b in 0..6} ( xz(p, i+a-3, j+b-3) + w[a,b] )
//
// R13 = R8 (best measured: 40.0us, VGPR 28) + T1 XCD-aware block swizzle.
// Grid (2,16,64) linear id = x+2y+32z round-robins XCDs -> every
// halo-sharing neighbor (adjacent y shares 6 rows = 19% of reads) lands
// on a different XCD's L2 -> all reuse is cross-XCD. Bijective chunked
// remap t=(old%8)*256+old/8 gives each XCD 8 complete planes: halo reuse
// becomes intra-XCD L2 hits. (2048%8==0 -> bijective, ERRATA#11 safe.)
// Everything else byte-identical to R8: 4x8 thread tile, 256x32 block
// tile, wave-uniform scalar row base + zero-row s_cselect, per-lane
// zero-page cndmask only on 2 edge chunks, SGPR weights, explicit max3
// tree, 1-deep prefetch, literal indices only.

#define HH 512
#define WW 512

__device__ __align__(16) const float ZROW[16] = {};  // zero page

__device__ __forceinline__ float max3f(float a, float b, float c) {
  float d;
  asm("v_max3_f32 %0, %1, %2, %3" : "=v"(d) : "v"(a), "v"(b), "v"(c));
  return d;
}

#define LOADROW(RV, K)                                                       \
  {                                                                          \
    const int r_ = row0 - 3 + (K);              /* scalar */                 \
    const float* rb_ = ((unsigned)r_ < (unsigned)HH)                         \
                           ? (xp + (ptrdiff_t)r_ * WW)                       \
                           : zrb;               /* s_cselect_b64 */          \
    const float* p0_ = okL ? rb_ + col0 - 4 : &ZROW[0];                      \
    const float* p2_ = okR ? rb_ + col0 + 4 : &ZROW[0];                      \
    float4 v0_ = *reinterpret_cast<const float4*>(p0_);                      \
    float4 v1_ = *reinterpret_cast<const float4*>(rb_ + col0);               \
    float4 v2_ = *reinterpret_cast<const float4*>(p2_);                      \
    RV[0] = v0_.x;  RV[1] = v0_.y;  RV[2] = v0_.z;  RV[3] = v0_.w;           \
    RV[4] = v1_.x;  RV[5] = v1_.y;  RV[6] = v1_.z;  RV[7] = v1_.w;           \
    RV[8] = v2_.x;  RV[9] = v2_.y;  RV[10] = v2_.z; RV[11] = v2_.w;          \
  }

// K is a literal at every expansion site; all indices fold at compile time.
#define COMPROW(RV, K)                                                       \
  {                                                                          \
    _Pragma("unroll") for (int t = 0; t < 8; ++t) {                          \
      if (t <= (K) && t + 6 >= (K)) { /* SE row a = K-t in 0..6 */           \
        const int a_ = (K) - t;                                              \
        _Pragma("unroll") for (int j = 0; j < 4; ++j) {                      \
          /* tap b: input col col0+j+b-3 -> RV[j+b+1] */                     \
          const float c0_ = RV[j + 1] + wv[a_ * 7 + 0];                      \
          const float c1_ = RV[j + 2] + wv[a_ * 7 + 1];                      \
          const float c2_ = RV[j + 3] + wv[a_ * 7 + 2];                      \
          const float c3_ = RV[j + 4] + wv[a_ * 7 + 3];                      \
          const float c4_ = RV[j + 5] + wv[a_ * 7 + 4];                      \
          const float c5_ = RV[j + 6] + wv[a_ * 7 + 5];                      \
          const float c6_ = RV[j + 7] + wv[a_ * 7 + 6];                      \
          const float t1_ = max3f(c0_, c1_, c2_);                            \
          const float t2_ = max3f(c3_, c4_, c5_);                            \
          acc[t][j] = ((K) == t)                                             \
                          ? max3f(t1_, t2_, c6_)          /* first touch */  \
                          : max3f(t1_, t2_, fmaxf(c6_, acc[t][j]));          \
        }                                                                    \
      }                                                                      \
    }                                                                        \
  }

#define STOREROW(T)                                                          \
  {                                                                          \
    float* orow_ = op + (ptrdiff_t)(row0 + (T)) * WW + col0;                 \
    *reinterpret_cast<float4*>(orow_) =                                      \
        make_float4(acc[T][0], acc[T][1], acc[T][2], acc[T][3]);             \
  }

__global__ __launch_bounds__(256) void dilate7(const float* __restrict__ x,
                                               const float* __restrict__ wg,
                                               float* __restrict__ out) {
  // ---- T1: bijective chunked XCD swizzle (nwg=2048, 256 ids per XCD) ----
  // HW dispatches linear ids round-robin across 8 XCDs; remap so XCD k
  // owns 256 CONSECUTIVE tiles = 8 complete planes (all halo reuse and
  // plane locality intra-XCD).
  const int oldid = (int)(blockIdx.x + 2u * blockIdx.y + 32u * blockIdx.z);
  const int t_ = (oldid & 7) * 256 + (oldid >> 3);
  const int bx = t_ & 1;           // 2 col-blocks
  const int by = (t_ >> 1) & 15;   // 16 row-blocks
  const int bz = t_ >> 5;          // 64 planes

  const int tid = threadIdx.x;
  const int lc = tid & 63;                          // 64 thread-cols per wave
  const int col0 = bx * 256 + lc * 4;               // output col base (mult 4)
  // tid>>6 is the wave id -> row0 is wave-uniform; force it scalar.
  const int row0 =
      __builtin_amdgcn_readfirstlane(by * 32 + (tid >> 6) * 8);

  const size_t plane_off = (size_t)bz * (size_t)(HH * WW);
  const float* xp = x + plane_off;
  float* op = out + plane_off;

  // Weights -> SGPRs (uniform loads).
  float wv[49];
#pragma unroll
  for (int i = 0; i < 49; ++i)
    wv[i] = __int_as_float(__builtin_amdgcn_readfirstlane(__float_as_int(wg[i])));

  const float* zrb = &ZROW[4];         // row base when the row is OOB
  const bool okL = (col0 >= 4);        // false only for global col0 == 0
  const bool okR = (col0 + 8 <= WW);   // false only for global col0 == 508

  float acc[8][4];                     // first write at K==t, no init needed
  float rvA[12], rvB[12];

  // 1-deep pipeline: load row K+1 while computing row K.
  LOADROW(rvA, 0);
  LOADROW(rvB, 1);   COMPROW(rvA, 0);
  LOADROW(rvA, 2);   COMPROW(rvB, 1);
  LOADROW(rvB, 3);   COMPROW(rvA, 2);
  LOADROW(rvA, 4);   COMPROW(rvB, 3);
  LOADROW(rvB, 5);   COMPROW(rvA, 4);
  LOADROW(rvA, 6);   COMPROW(rvB, 5);
  LOADROW(rvB, 7);   COMPROW(rvA, 6);   STOREROW(0);
  LOADROW(rvA, 8);   COMPROW(rvB, 7);   STOREROW(1);
  LOADROW(rvB, 9);   COMPROW(rvA, 8);   STOREROW(2);
  LOADROW(rvA, 10);  COMPROW(rvB, 9);   STOREROW(3);
  LOADROW(rvB, 11);  COMPROW(rvA, 10);  STOREROW(4);
  LOADROW(rvA, 12);  COMPROW(rvB, 11);  STOREROW(5);
  LOADROW(rvB, 13);  COMPROW(rvA, 12);  STOREROW(6);
  COMPROW(rvB, 13);  STOREROW(7);
}

extern "C" void kernel_launch(void* const* d_in, const int* in_sizes, int n_in,
                              void* d_out, int out_size, void* d_ws, size_t ws_size,
                              hipStream_t stream) {
  const float* x = (const float*)d_in[0];
  const float* w = (const float*)d_in[1];
  float* out = (float*)d_out;
  const int planes = in_sizes[0] / (HH * WW);   // 8*8 = 64
  dim3 grid(2, 16, planes);                     // 256x32 tile -> exact cover
  dilate7<<<grid, dim3(256, 1, 1), 0, stream>>>(x, w, out);
}